// Round 5
// baseline (256.587 us; speedup 1.0000x reference)
//
#include <hip/hip_runtime.h>
#include <hip/hip_bf16.h>
#include <stdint.h>

#define M_DIM 4096
#define N_DIM 4096
#define K_DIM 2048

typedef __bf16 bf16x8 __attribute__((ext_vector_type(8)));
typedef float f32x4 __attribute__((ext_vector_type(4)));
typedef unsigned short u16x8 __attribute__((ext_vector_type(8)));

// ---------------- fp32 -> bf16 (RNE) ----------------
__device__ __forceinline__ unsigned short f32_to_bf16(float f) {
  union { float f; unsigned int u; } c; c.f = f;
  unsigned int u = c.u;
  unsigned int r = (u + 0x7FFFu + ((u >> 16) & 1u)) >> 16;
  return (unsigned short)r;
}

// Blocks [0, 4096): convert x with XOR column-granule swizzle (granule g of
// row r within each 64-col K-tile holds source granule g ^ (r&7)) so the
// forced-linear global_load_lds staging yields a conflict-free LDS tile.
// Blocks [4096, 8192): convert W plainly (W is read directly from global in
// the GEMM, fragment-addressed, so it must stay unswizzled).
// Block 0 additionally zeroes S.
__global__ void __launch_bounds__(256) cvt_kernel(
    const float* __restrict__ x, const float* __restrict__ w,
    unsigned short* __restrict__ xb, unsigned short* __restrict__ wb,
    float* __restrict__ S) {
  if (blockIdx.x == 0) {
#pragma unroll
    for (int k = 0; k < 16; ++k)
      S[threadIdx.x + k * 256] = 0.f;
  }

  const int nG = M_DIM * K_DIM / 8;  // granules per tensor
  int i = blockIdx.x * 256 + threadIdx.x;
  if (i < nG) {
    // x: swizzled granule gather
    const int row = i >> 8;        // K/8 = 256 granules per row
    const int cg  = i & 255;
    const int kt  = cg >> 3;
    const int g   = cg & 7;
    const int sg  = g ^ (row & 7);
    const float4* s4 = (const float4*)(x + (size_t)row * K_DIM + kt * 64 + sg * 8);
    float4 f0 = s4[0], f1 = s4[1];
    u16x8 o;
    o[0] = f32_to_bf16(f0.x); o[1] = f32_to_bf16(f0.y);
    o[2] = f32_to_bf16(f0.z); o[3] = f32_to_bf16(f0.w);
    o[4] = f32_to_bf16(f1.x); o[5] = f32_to_bf16(f1.y);
    o[6] = f32_to_bf16(f1.z); o[7] = f32_to_bf16(f1.w);
    ((u16x8*)xb)[i] = o;
  } else {
    // W: straight convert
    const int gid = i - nG;
    const float4* s4 = (const float4*)(w + (size_t)gid * 8);
    float4 f0 = s4[0], f1 = s4[1];
    u16x8 o;
    o[0] = f32_to_bf16(f0.x); o[1] = f32_to_bf16(f0.y);
    o[2] = f32_to_bf16(f0.z); o[3] = f32_to_bf16(f0.w);
    o[4] = f32_to_bf16(f1.x); o[5] = f32_to_bf16(f1.y);
    o[6] = f32_to_bf16(f1.z); o[7] = f32_to_bf16(f1.w);
    ((u16x8*)wb)[gid] = o;
  }
}

// ---------------- async global -> LDS, 16B per lane ----------------
__device__ __forceinline__ void gload_lds16(const unsigned short* g, unsigned short* l) {
  __builtin_amdgcn_global_load_lds(
      (const __attribute__((address_space(1))) unsigned int*)g,
      (__attribute__((address_space(3))) unsigned int*)l,
      16, 0, 0);
}

// ---------------- fused GEMM -> clamp -> sum exp(v-10) per row ----------------
// 128x128 tile, BK=64, 4 waves (64x64 quadrants), 4x4 16x16x32 bf16 MFMA frags.
// A goes through LDS (swizzled, conflict-free). B fragments are loaded
// DIRECTLY from global (L2/L3-resident; no barrier dependency -> prefetchable)
// halving the LDS-read pipe load, which was the critical path (~41 us/CU).
__global__ void __launch_bounds__(256) gemm_lse_kernel(
    const unsigned short* __restrict__ xb,   // [M][K] bf16, swizzled granules
    const unsigned short* __restrict__ wb,   // [N][K] bf16, plain
    const float* __restrict__ bias,          // [N]
    float* __restrict__ S) {                 // [M] partial sums of exp(clamp(v)-10)
  __shared__ __align__(16) unsigned short As[128 * 64];

  const int tid = threadIdx.x;
  const int bm0 = blockIdx.y * 128;
  const int bn0 = blockIdx.x * 128;

  const int wave = tid >> 6, lane = tid & 63;
  const int wr = (wave >> 1) * 64;
  const int wc = (wave & 1) * 64;
  const int lr = lane & 15;
  const int q  = lane >> 4;

  f32x4 acc[4][4];
  const f32x4 zero = {0.f, 0.f, 0.f, 0.f};
#pragma unroll
  for (int mi = 0; mi < 4; ++mi)
#pragma unroll
    for (int ni = 0; ni < 4; ++ni)
      acc[mi][ni] = zero;

  const int srow = tid >> 3;
  const int scol = (tid & 7) * 8;

  const unsigned short* xg = xb + (size_t)(bm0 + srow) * K_DIM + scol;
  unsigned short* lA = As + srow * 64 + scol;

  // B fragment row pointers (4 rows per lane, fixed; k advances with kt/ks)
  const unsigned short* wrow[4];
#pragma unroll
  for (int i = 0; i < 4; ++i)
    wrow[i] = wb + (size_t)(bn0 + wc + i * 16 + lr) * K_DIM + q * 8;

  for (int kt = 0; kt < K_DIM / 64; ++kt) {
    const int k0 = kt * 64;
#pragma unroll
    for (int c = 0; c < 4; ++c)   // 4 calls cover 128 A-rows
      gload_lds16(xg + (size_t)(c * 32) * K_DIM + k0, lA + c * 32 * 64);
    __syncthreads();

#pragma unroll
    for (int ks = 0; ks < 2; ++ks) {
      // A: granule G = ks*4 + q; swizzled col = (G ^ (lr&7)) * 8
      const int swcol = ((ks * 4 + q) ^ (lr & 7)) * 8;
      bf16x8 af[4], bfr[4];
#pragma unroll
      for (int i = 0; i < 4; ++i) {
        af[i]  = *(const bf16x8*)(As + (wr + i * 16 + lr) * 64 + swcol);
        bfr[i] = *(const bf16x8*)(wrow[i] + k0 + ks * 32);   // direct global
      }
#pragma unroll
      for (int mi = 0; mi < 4; ++mi)
#pragma unroll
        for (int ni = 0; ni < 4; ++ni)
          acc[mi][ni] = __builtin_amdgcn_mfma_f32_16x16x32_bf16(
              af[mi], bfr[ni], acc[mi][ni], 0, 0, 0);
    }
    __syncthreads();
  }

  // Epilogue: bias + clamp + exp(v-10); reduce 16 lanes; one plain atomic/row.
  float bv[4];
#pragma unroll
  for (int ni = 0; ni < 4; ++ni)
    bv[ni] = bias[bn0 + wc + ni * 16 + lr];

#pragma unroll
  for (int mi = 0; mi < 4; ++mi) {
#pragma unroll
    for (int reg = 0; reg < 4; ++reg) {
      float s = 0.f;
#pragma unroll
      for (int ni = 0; ni < 4; ++ni) {
        float v = acc[mi][ni][reg] + bv[ni];  // SCALE_FACTOR*2 == 1.0
        v = fminf(fmaxf(v, -10.f), 10.f);
        s += __expf(v - 10.f);
      }
      s += __shfl_xor(s, 1);
      s += __shfl_xor(s, 2);
      s += __shfl_xor(s, 4);
      s += __shfl_xor(s, 8);
      if (lr == 0)
        atomicAdd(&S[bm0 + wr + mi * 16 + q * 4 + reg], s);
    }
  }
}

// ---------------- finalize: lse = 10 + log(S); mish(lse) ----------------
__global__ void __launch_bounds__(256) finalize_kernel(const float* __restrict__ S,
                                                       float* __restrict__ out) {
  int i = blockIdx.x * blockDim.x + threadIdx.x;
  float lse = 10.0f + logf(S[i]);
  float sp = fmaxf(lse, 0.f) + log1pf(expf(-fabsf(lse)));  // stable softplus
  out[i] = lse * tanhf(sp);
}

extern "C" void kernel_launch(void* const* d_in, const int* in_sizes, int n_in,
                              void* d_out, int out_size, void* d_ws, size_t ws_size,
                              hipStream_t stream) {
  const float* x = (const float*)d_in[0];   // [4096, 2048]
  const float* W = (const float*)d_in[1];   // [4096, 2048]
  const float* b = (const float*)d_in[2];   // [4096]
  float* out = (float*)d_out;               // [4096]

  char* ws = (char*)d_ws;
  float* S = (float*)ws;                                       // 16 KB
  unsigned short* xb = (unsigned short*)(ws + 16384);          // 16 MB
  unsigned short* wb = (unsigned short*)(ws + 16384 + (size_t)M_DIM * K_DIM * 2);

  const int nG2 = 2 * M_DIM * K_DIM / 8;  // both tensors, 16B granules
  cvt_kernel<<<nG2 / 256, 256, 0, stream>>>(x, W, xb, wb, S);

  dim3 grid(N_DIM / 128, M_DIM / 128);  // 32 x 32 = 1024 blocks
  gemm_lse_kernel<<<grid, 256, 0, stream>>>(xb, wb, b, S);

  finalize_kernel<<<M_DIM / 256, 256, 0, stream>>>(S, out);
}

// Round 6
// 157.348 us; speedup vs baseline: 1.6307x; 1.6307x over previous
//
#include <hip/hip_runtime.h>
#include <hip/hip_bf16.h>
#include <stdint.h>

#define M_DIM 4096
#define N_DIM 4096
#define K_DIM 2048

typedef __bf16 bf16x8 __attribute__((ext_vector_type(8)));
typedef float f32x4 __attribute__((ext_vector_type(4)));
typedef unsigned short u16x8 __attribute__((ext_vector_type(8)));

// ---------------- fp32 -> bf16 (RNE) ----------------
__device__ __forceinline__ unsigned short f32_to_bf16(float f) {
  union { float f; unsigned int u; } c; c.f = f;
  unsigned int u = c.u;
  unsigned int r = (u + 0x7FFFu + ((u >> 16) & 1u)) >> 16;
  return (unsigned short)r;
}

// Convert BOTH tensors fp32->bf16 with the XOR column-granule swizzle
// (granule g of row r within each 64-col K-tile holds source granule
// g ^ (r&7)) so the forced-linear global_load_lds staging yields a
// bank-conflict-free LDS tile. Block 0 additionally zeroes S.
__global__ void __launch_bounds__(256) cvt_swz_kernel(
    const float* __restrict__ x, const float* __restrict__ w,
    unsigned short* __restrict__ xb, unsigned short* __restrict__ wb,
    float* __restrict__ S) {
  if (blockIdx.x == 0) {
#pragma unroll
    for (int k = 0; k < 16; ++k)
      S[threadIdx.x + k * 256] = 0.f;
  }

  const int nG = M_DIM * K_DIM / 8;  // granules per tensor
  int i = blockIdx.x * 256 + threadIdx.x;
  const float* src;
  unsigned short* dst;
  int gid;
  if (i < nG) { src = x; dst = xb; gid = i; }
  else        { src = w; dst = wb; gid = i - nG; }

  const int row = gid >> 8;        // K/8 = 256 granules per row
  const int cg  = gid & 255;
  const int kt  = cg >> 3;
  const int g   = cg & 7;
  const int sg  = g ^ (row & 7);   // swizzled source granule

  const float4* s4 = (const float4*)(src + (size_t)row * K_DIM + kt * 64 + sg * 8);
  float4 f0 = s4[0], f1 = s4[1];
  u16x8 o;
  o[0] = f32_to_bf16(f0.x); o[1] = f32_to_bf16(f0.y);
  o[2] = f32_to_bf16(f0.z); o[3] = f32_to_bf16(f0.w);
  o[4] = f32_to_bf16(f1.x); o[5] = f32_to_bf16(f1.y);
  o[6] = f32_to_bf16(f1.z); o[7] = f32_to_bf16(f1.w);
  ((u16x8*)dst)[gid] = o;
}

// ---------------- async global -> LDS, 16B per lane ----------------
__device__ __forceinline__ void gload_lds16(const unsigned short* g, unsigned short* l) {
  __builtin_amdgcn_global_load_lds(
      (const __attribute__((address_space(1))) unsigned int*)g,
      (__attribute__((address_space(3))) unsigned int*)l,
      16, 0, 0);
}

// ---------------- fused GEMM -> clamp -> sum exp(v-10) per row ----------------
// 128x256 block tile, BK=64, 4 waves each computing 64x128 (4x8 grid of
// 16x16x32 bf16 MFMA frags). 4x8 raises MFMA-per-LDS-read from 2.0 to 2.67,
// cutting the LDS pipe (the measured critical path of the 4x4 version:
// 41us reads + 27us staging writes per CU) by ~25%/~21%.
// LDS tiles are column-granule swizzled (see cvt_swz_kernel) -> 0 conflicts.
__global__ void __launch_bounds__(256, 2) gemm_lse_kernel(
    const unsigned short* __restrict__ xb,   // [M][K] bf16, swizzled granules
    const unsigned short* __restrict__ wb,   // [N][K] bf16, swizzled granules
    const float* __restrict__ bias,          // [N]
    float* __restrict__ S) {                 // [M] partial sums of exp(clamp(v)-10)
  __shared__ __align__(16) unsigned short As[128 * 64];
  __shared__ __align__(16) unsigned short Bs[256 * 64];

  const int tid = threadIdx.x;
  const int bm0 = blockIdx.y * 128;
  const int bn0 = blockIdx.x * 256;

  const int wave = tid >> 6, lane = tid & 63;
  const int wr = (wave & 1) * 64;    // wave row offset (0/64)
  const int wc = (wave >> 1) * 128;  // wave col offset (0/128)
  const int lr = lane & 15;
  const int q  = lane >> 4;

  f32x4 acc[4][8];
  const f32x4 zero = {0.f, 0.f, 0.f, 0.f};
#pragma unroll
  for (int mi = 0; mi < 4; ++mi)
#pragma unroll
    for (int ni = 0; ni < 8; ++ni)
      acc[mi][ni] = zero;

  const int srow = tid >> 3;        // 0..31
  const int scol = (tid & 7) * 8;

  const unsigned short* xg = xb + (size_t)(bm0 + srow) * K_DIM + scol;
  const unsigned short* wg = wb + (size_t)(bn0 + srow) * K_DIM + scol;
  unsigned short* lA = As + srow * 64 + scol;
  unsigned short* lB = Bs + srow * 64 + scol;

  for (int kt = 0; kt < K_DIM / 64; ++kt) {
    const int k0 = kt * 64;
#pragma unroll
    for (int c = 0; c < 4; ++c)     // 128 A-rows
      gload_lds16(xg + (size_t)(c * 32) * K_DIM + k0, lA + c * 32 * 64);
#pragma unroll
    for (int c = 0; c < 8; ++c)     // 256 B-rows
      gload_lds16(wg + (size_t)(c * 32) * K_DIM + k0, lB + c * 32 * 64);
    __syncthreads();

#pragma unroll
    for (int ks = 0; ks < 2; ++ks) {
      // granule G = ks*4 + q; swizzled col = (G ^ (lr&7)) * 8
      // (row & 7 == lr & 7 for every fragment row: wr, wc, i*16 mult. of 8)
      const int swcol = ((ks * 4 + q) ^ (lr & 7)) * 8;
      bf16x8 af[4], bfr[8];
#pragma unroll
      for (int i = 0; i < 4; ++i)
        af[i]  = *(const bf16x8*)(As + (wr + i * 16 + lr) * 64 + swcol);
#pragma unroll
      for (int i = 0; i < 8; ++i)
        bfr[i] = *(const bf16x8*)(Bs + (wc + i * 16 + lr) * 64 + swcol);
#pragma unroll
      for (int mi = 0; mi < 4; ++mi)
#pragma unroll
        for (int ni = 0; ni < 8; ++ni)
          acc[mi][ni] = __builtin_amdgcn_mfma_f32_16x16x32_bf16(
              af[mi], bfr[ni], acc[mi][ni], 0, 0, 0);
    }
    __syncthreads();
  }

  // Epilogue: bias + clamp + exp(v-10); reduce across 16 lanes (128 cols);
  // one fire-and-forget atomic per row per wave.
  float bv[8];
#pragma unroll
  for (int ni = 0; ni < 8; ++ni)
    bv[ni] = bias[bn0 + wc + ni * 16 + lr];

#pragma unroll
  for (int mi = 0; mi < 4; ++mi) {
#pragma unroll
    for (int reg = 0; reg < 4; ++reg) {
      float s = 0.f;
#pragma unroll
      for (int ni = 0; ni < 8; ++ni) {
        float v = acc[mi][ni][reg] + bv[ni];  // SCALE_FACTOR*2 == 1.0
        v = fminf(fmaxf(v, -10.f), 10.f);
        s += __expf(v - 10.f);
      }
      s += __shfl_xor(s, 1);
      s += __shfl_xor(s, 2);
      s += __shfl_xor(s, 4);
      s += __shfl_xor(s, 8);
      if (lr == 0)
        atomicAdd(&S[bm0 + wr + mi * 16 + q * 4 + reg], s);
    }
  }
}

// ---------------- finalize: lse = 10 + log(S); mish(lse) ----------------
__global__ void __launch_bounds__(256) finalize_kernel(const float* __restrict__ S,
                                                       float* __restrict__ out) {
  int i = blockIdx.x * blockDim.x + threadIdx.x;
  float lse = 10.0f + logf(S[i]);
  float sp = fmaxf(lse, 0.f) + log1pf(expf(-fabsf(lse)));  // stable softplus
  out[i] = lse * tanhf(sp);
}

extern "C" void kernel_launch(void* const* d_in, const int* in_sizes, int n_in,
                              void* d_out, int out_size, void* d_ws, size_t ws_size,
                              hipStream_t stream) {
  const float* x = (const float*)d_in[0];   // [4096, 2048]
  const float* W = (const float*)d_in[1];   // [4096, 2048]
  const float* b = (const float*)d_in[2];   // [4096]
  float* out = (float*)d_out;               // [4096]

  char* ws = (char*)d_ws;
  float* S = (float*)ws;                                       // 16 KB
  unsigned short* xb = (unsigned short*)(ws + 16384);          // 16 MB
  unsigned short* wb = (unsigned short*)(ws + 16384 + (size_t)M_DIM * K_DIM * 2);

  const int nG2 = 2 * M_DIM * K_DIM / 8;  // both tensors, 16B granules
  cvt_swz_kernel<<<nG2 / 256, 256, 0, stream>>>(x, W, xb, wb, S);

  dim3 grid(N_DIM / 256, M_DIM / 128);  // 16 x 32 = 512 blocks (2/CU)
  gemm_lse_kernel<<<grid, 256, 0, stream>>>(xb, wb, b, S);

  finalize_kernel<<<M_DIM / 256, 256, 0, stream>>>(S, out);
}